// Round 3
// baseline (119.940 us; speedup 1.0000x reference)
//
#include <hip/hip_runtime.h>
#include <hip/hip_bf16.h>

#define IH   48
#define IW   48
#define CH   64
#define KS   7
#define LN_EPS 1e-5f
#define QSCALE 0.35355339059327373f
#define L2E    1.4426950408889634f

#define TS   8                   /* output tile side (8x8 = 64 px) */
#define HS   14                  /* halo side: 8 + 2*3 */
#define HP   196                 /* halo pixels 14*14 */
#define KVS  136                 /* kv LDS row stride bf16 (272 B = 68 dwords:
                                    row r starts at bank 4r%32 -> 8 consecutive
                                    rows tile all 32 banks; was 128 (256 B), an
                                    8-way conflict on every ds_read_b128) */
#define AOS  72                  /* q / attn-out LDS row stride bf16 (144 B) */

typedef __bf16 bf16_t;
typedef bf16_t bf16x8 __attribute__((ext_vector_type(8)));
typedef float  f32x4  __attribute__((ext_vector_type(4)));
typedef float  f32x2  __attribute__((ext_vector_type(2)));

__device__ __forceinline__ float bflo(unsigned u) { union { unsigned i; float f; } v; v.i = u << 16; return v.f; }
__device__ __forceinline__ float bfhi(unsigned u) { union { unsigned i; float f; } v; v.i = u & 0xffff0000u; return v.f; }
__device__ __forceinline__ f32x2 unp2(unsigned u) { f32x2 r; r.x = bflo(u); r.y = bfhi(u); return r; }

__device__ __forceinline__ float4 ldf4u(const float* p) {
    float4 r; __builtin_memcpy(&r, p, 16); return r;
}

__device__ __forceinline__ bf16x8 pack_bf16x8(float4 lo, float4 hi) {
    bf16x8 r;
    r[0] = (bf16_t)lo.x; r[1] = (bf16_t)lo.y; r[2] = (bf16_t)lo.z; r[3] = (bf16_t)lo.w;
    r[4] = (bf16_t)hi.x; r[5] = (bf16_t)hi.y; r[6] = (bf16_t)hi.z; r[7] = (bf16_t)hi.w;
    return r;
}

// One block per 8x8 output tile. 512 threads (8 waves), 2 blocks/CU (62.5 KB).
// Phase A: QKV projection (MFMA) -> q (LDS, stride AOS) + K/V halo (LDS, KVS).
// Phase B: one thread per (pixel, head); uniform 7x7 window; conflict-free
//          ds_read_b128 (KVS=136); exp2-folded softmax taps.
// Phase C: proj + LN (MFMA), waves 0-3.
__global__ __launch_bounds__(512, 4) void fused_na_kernel(
        const float* __restrict__ x,
        const float* __restrict__ w,      // qkv_w [192][64]
        const float* __restrict__ b,      // qkv_b [192]
        const float* __restrict__ rpb,
        const float* __restrict__ pw,     // proj_w [64][64]
        const float* __restrict__ pb,
        const float* __restrict__ g,
        const float* __restrict__ beta,
        float* __restrict__ out) {
    __shared__ __align__(16) __hip_bfloat16 kv[HP * KVS];    // 53,312 B
    __shared__ __align__(16) __hip_bfloat16 qao[64 * AOS];   //  9,216 B

    const int blk  = blockIdx.x;         // 0..575
    const int n    = blk & 15;           // image
    const int tile = blk >> 4;           // 0..35
    const int i0   = (tile / 6) * TS;
    const int j0   = (tile % 6) * TS;
    int h0 = i0 - 3; h0 = h0 < 0 ? 0 : (h0 > IH - HS ? IH - HS : h0);
    int w0 = j0 - 3; w0 = w0 < 0 ? 0 : (w0 > IW - HS ? IW - HS : w0);
    const int tid = threadIdx.x;
    const size_t img = (size_t)n * (IH * IW);

    // ---------------- phase A: QKV -> LDS --------------------------------
    {
        const int wv = tid >> 6;         // 0..7
        const int l  = tid & 63;
        const int m  = l & 15;
        const int kg = l >> 4;

        // ---- Q: interior 64 px, waves 0-3 (one 16-px m-tile each) ----
        if (wv < 4) {
            const int ch_base = m * 4;
            const float4 bias4 = *(const float4*)(b + ch_base);
            bf16x8 wb0[4], wb1[4];
            #pragma unroll
            for (int t = 0; t < 4; ++t) {
                const float* wr_ = w + (size_t)(ch_base + t) * CH + kg * 8;
                wb0[t] = pack_bf16x8(*(const float4*)(wr_),      *(const float4*)(wr_ + 4));
                wb1[t] = pack_bf16x8(*(const float4*)(wr_ + 32), *(const float4*)(wr_ + 36));
            }
            const int px = wv * 16 + m;
            const int hr = i0 + (px >> 3);
            const int wc = j0 + (px & 7);
            const float* xr = x + (img + hr * IW + wc) * CH + kg * 8;
            const bf16x8 a0 = pack_bf16x8(*(const float4*)(xr),      *(const float4*)(xr + 4));
            const bf16x8 a1 = pack_bf16x8(*(const float4*)(xr + 32), *(const float4*)(xr + 36));
            float val[4][4];
            #pragma unroll
            for (int t = 0; t < 4; ++t) {
                f32x4 acc = {0.f, 0.f, 0.f, 0.f};
                acc = __builtin_amdgcn_mfma_f32_16x16x32_bf16(a0, wb0[t], acc, 0, 0, 0);
                acc = __builtin_amdgcn_mfma_f32_16x16x32_bf16(a1, wb1[t], acc, 0, 0, 0);
                const float bias = (t == 0) ? bias4.x : (t == 1) ? bias4.y : (t == 2) ? bias4.z : bias4.w;
                #pragma unroll
                for (int rr = 0; rr < 4; ++rr) val[t][rr] = (acc[rr] + bias) * (QSCALE * L2E);
            }
            #pragma unroll
            for (int rr = 0; rr < 4; ++rr) {
                const int pix = wv * 16 + kg * 4 + rr;
                union { ushort4 u; __hip_bfloat16 hh[4]; } pk;
                #pragma unroll
                for (int t = 0; t < 4; ++t) pk.hh[t] = __float2bfloat16(val[t][rr]);
                *reinterpret_cast<ushort4*>(qao + pix * AOS + ch_base) = pk.u;
            }
        }

        // ---- K,V: 196 halo px. grp fixed per wave-half; 13 m-tiles / 4 ----
        {
            const int grp = 1 + (wv >> 2);               // waves 0-3: K, 4-7: V
            const int ch_base = grp * 64 + m * 4;
            const float4 bias4 = *(const float4*)(b + ch_base);
            bf16x8 wb0[4], wb1[4];
            #pragma unroll
            for (int t = 0; t < 4; ++t) {
                const float* wr_ = w + (size_t)(ch_base + t) * CH + kg * 8;
                wb0[t] = pack_bf16x8(*(const float4*)(wr_),      *(const float4*)(wr_ + 4));
                wb1[t] = pack_bf16x8(*(const float4*)(wr_ + 32), *(const float4*)(wr_ + 36));
            }
            for (int mt = wv & 3; mt < 13; mt += 4) {
                int hp = mt * 16 + m; if (hp > HP - 1) hp = HP - 1;   // clamped A-row feeds only skipped D-rows
                const int hr = h0 + hp / HS;
                const int wc = w0 + hp % HS;
                const float* xr = x + (img + hr * IW + wc) * CH + kg * 8;
                const bf16x8 a0 = pack_bf16x8(*(const float4*)(xr),      *(const float4*)(xr + 4));
                const bf16x8 a1 = pack_bf16x8(*(const float4*)(xr + 32), *(const float4*)(xr + 36));
                float val[4][4];
                #pragma unroll
                for (int t = 0; t < 4; ++t) {
                    f32x4 acc = {0.f, 0.f, 0.f, 0.f};
                    acc = __builtin_amdgcn_mfma_f32_16x16x32_bf16(a0, wb0[t], acc, 0, 0, 0);
                    acc = __builtin_amdgcn_mfma_f32_16x16x32_bf16(a1, wb1[t], acc, 0, 0, 0);
                    const float bias = (t == 0) ? bias4.x : (t == 1) ? bias4.y : (t == 2) ? bias4.z : bias4.w;
                    #pragma unroll
                    for (int rr = 0; rr < 4; ++rr) val[t][rr] = acc[rr] + bias;
                }
                #pragma unroll
                for (int rr = 0; rr < 4; ++rr) {
                    const int pix = mt * 16 + kg * 4 + rr;
                    if (pix < HP) {
                        union { ushort4 u; __hip_bfloat16 hh[4]; } pk;
                        #pragma unroll
                        for (int t = 0; t < 4; ++t) pk.hh[t] = __float2bfloat16(val[t][rr]);
                        *reinterpret_cast<ushort4*>(kv + pix * KVS + (grp - 1) * 64 + m * 4) = pk.u;
                    }
                }
            }
        }
    }
    __syncthreads();

    // ---------------- phase B: per-(pixel,head) attention, K/V in LDS ----
    {
        const int h  = tid & 7;
        const int px = tid >> 3;             // 0..63
        const int i  = i0 + (px >> 3);
        const int j  = j0 + (px & 7);

        f32x2 q0[4];
        {
            const uint4 u = *reinterpret_cast<const uint4*>(qao + px * AOS + h * 8);
            q0[0] = unp2(u.x); q0[1] = unp2(u.y); q0[2] = unp2(u.z); q0[3] = unp2(u.w);
        }
        __syncthreads();                     // qao region reused for attn-out

        int si = i - 3;  si = si < 0 ? 0 : (si > IH - KS ? IH - KS : si);
        int sj = j - 3;  sj = sj < 0 ? 0 : (sj > IW - KS ? IW - KS : sj);
        const float* rpc = rpb + h * (2*KS-1) * (2*KS-1)
                               + (si - i + (KS-1)) * (2*KS-1) + (sj - j + (KS-1));
        const __hip_bfloat16* kbase = kv + ((si - h0) * HS + (sj - w0)) * KVS + h * 8;

        float lr = 0.f;
        f32x2 a[4];
        #pragma unroll
        for (int d = 0; d < 4; ++d) a[d] = (f32x2){0.f, 0.f};

        for (int p = 0; p < KS; ++p) {       // uniform 7 rows, no divergence
            const __hip_bfloat16* row = kbase + p * (HS * KVS);
            uint4 kb[KS], vb[KS];
            #pragma unroll
            for (int qq = 0; qq < KS; ++qq) {
                kb[qq] = *reinterpret_cast<const uint4*>(row + qq * KVS);
                vb[qq] = *reinterpret_cast<const uint4*>(row + qq * KVS + 64);
            }
            const float* rr = rpc + p * (2*KS-1);
            const float4 ba = ldf4u(rr);
            const float4 bb = ldf4u(rr + 3);

            float s[KS];
            #pragma unroll
            for (int qq = 0; qq < KS; ++qq) {
                const f32x2 k0 = unp2(kb[qq].x), k1 = unp2(kb[qq].y);
                const f32x2 k2 = unp2(kb[qq].z), k3 = unp2(kb[qq].w);
                f32x2 t = q0[0]*k0 + q0[1]*k1 + q0[2]*k2 + q0[3]*k3;
                s[qq] = t.x + t.y;
            }
            float e[KS];
            e[0] = __builtin_amdgcn_exp2f(fmaf(ba.x, L2E, s[0]));
            e[1] = __builtin_amdgcn_exp2f(fmaf(ba.y, L2E, s[1]));
            e[2] = __builtin_amdgcn_exp2f(fmaf(ba.z, L2E, s[2]));
            e[3] = __builtin_amdgcn_exp2f(fmaf(ba.w, L2E, s[3]));
            e[4] = __builtin_amdgcn_exp2f(fmaf(bb.y, L2E, s[4]));
            e[5] = __builtin_amdgcn_exp2f(fmaf(bb.z, L2E, s[5]));
            e[6] = __builtin_amdgcn_exp2f(fmaf(bb.w, L2E, s[6]));

            #pragma unroll
            for (int qq = 0; qq < KS; ++qq) {
                const f32x2 v0 = unp2(vb[qq].x), v1 = unp2(vb[qq].y);
                const f32x2 v2 = unp2(vb[qq].z), v3 = unp2(vb[qq].w);
                lr += e[qq];
                a[0] += e[qq] * v0; a[1] += e[qq] * v1;
                a[2] += e[qq] * v2; a[3] += e[qq] * v3;
            }
        }
        const float inv = 1.f / lr;
        union { uint4 u; __hip_bfloat16 hh[8]; } pk;
        #pragma unroll
        for (int d = 0; d < 4; ++d) {
            pk.hh[2*d]   = __float2bfloat16(a[d].x * inv);
            pk.hh[2*d+1] = __float2bfloat16(a[d].y * inv);
        }
        *reinterpret_cast<uint4*>(qao + px * AOS + h * 8) = pk.u;
    }
    __syncthreads();

    // ---------------- phase C: proj + LN (waves 0-3, 4 m-tiles) ----------
    if ((tid >> 6) < 4) {
        const int wv = tid >> 6;             // 0..3
        const int l  = tid & 63;
        const int m  = l & 15;
        const int kg = l >> 4;

        const __hip_bfloat16* ar = qao + (wv * 16 + m) * AOS + kg * 8;
        const bf16x8 a0 = *reinterpret_cast<const bf16x8*>(ar);
        const bf16x8 a1 = *reinterpret_cast<const bf16x8*>(ar + 32);

        const int ch_base = m * 4;
        const float4 bias4 = *(const float4*)(pb + ch_base);

        float val[4][4];                                   // [t][r], ch = m*4+t
        #pragma unroll
        for (int t = 0; t < 4; ++t) {
            const float* wr_ = pw + (size_t)(ch_base + t) * CH + kg * 8;  // permuted B row
            const bf16x8 b0 = pack_bf16x8(*(const float4*)(wr_),      *(const float4*)(wr_ + 4));
            const bf16x8 b1 = pack_bf16x8(*(const float4*)(wr_ + 32), *(const float4*)(wr_ + 36));
            f32x4 acc = {0.f, 0.f, 0.f, 0.f};
            acc = __builtin_amdgcn_mfma_f32_16x16x32_bf16(a0, b0, acc, 0, 0, 0);
            acc = __builtin_amdgcn_mfma_f32_16x16x32_bf16(a1, b1, acc, 0, 0, 0);
            const float bias = (t == 0) ? bias4.x : (t == 1) ? bias4.y : (t == 2) ? bias4.z : bias4.w;
            #pragma unroll
            for (int r = 0; r < 4; ++r) val[t][r] = acc[r] + bias;
        }

        float sm[4];
        #pragma unroll
        for (int r = 0; r < 4; ++r) sm[r] = val[0][r] + val[1][r] + val[2][r] + val[3][r];
        #pragma unroll
        for (int mask = 1; mask <= 8; mask <<= 1) {
            #pragma unroll
            for (int r = 0; r < 4; ++r) sm[r] += __shfl_xor(sm[r], mask, 64);
        }
        float mu[4];
        #pragma unroll
        for (int r = 0; r < 4; ++r) mu[r] = sm[r] * (1.f / 64.f);

        float qs[4];
        #pragma unroll
        for (int r = 0; r < 4; ++r) {
            float aa = val[0][r] - mu[r], bq = val[1][r] - mu[r];
            float c  = val[2][r] - mu[r], d  = val[3][r] - mu[r];
            qs[r] = aa * aa + bq * bq + c * c + d * d;
        }
        #pragma unroll
        for (int mask = 1; mask <= 8; mask <<= 1) {
            #pragma unroll
            for (int r = 0; r < 4; ++r) qs[r] += __shfl_xor(qs[r], mask, 64);
        }
        float rs[4];
        #pragma unroll
        for (int r = 0; r < 4; ++r) rs[r] = rsqrtf(qs[r] * (1.f / 64.f) + LN_EPS);

        const float4 g4  = *(const float4*)(g + ch_base);
        const float4 be4 = *(const float4*)(beta + ch_base);
        #pragma unroll
        for (int r = 0; r < 4; ++r) {
            const int pl = wv * 16 + kg * 4 + r;          // local pixel 0..63
            const int gi = i0 + (pl >> 3), gj = j0 + (pl & 7);
            float4 o;
            o.x = (val[0][r] - mu[r]) * rs[r] * g4.x + be4.x;
            o.y = (val[1][r] - mu[r]) * rs[r] * g4.y + be4.y;
            o.z = (val[2][r] - mu[r]) * rs[r] * g4.z + be4.z;
            o.w = (val[3][r] - mu[r]) * rs[r] * g4.w + be4.w;
            *reinterpret_cast<float4*>(out + (img + gi * IW + gj) * CH + ch_base) = o;
        }
    }
}

extern "C" void kernel_launch(void* const* d_in, const int* in_sizes, int n_in,
                              void* d_out, int out_size, void* d_ws, size_t ws_size,
                              hipStream_t stream) {
    const float* x      = (const float*)d_in[0];
    const float* qkv_w  = (const float*)d_in[1];
    const float* qkv_b  = (const float*)d_in[2];
    const float* proj_w = (const float*)d_in[3];
    const float* proj_b = (const float*)d_in[4];
    const float* rpb    = (const float*)d_in[5];
    const float* ln_g   = (const float*)d_in[6];
    const float* ln_b   = (const float*)d_in[7];
    float* out = (float*)d_out;

    fused_na_kernel<<<576, 512, 0, stream>>>(x, qkv_w, qkv_b, rpb,
                                             proj_w, proj_b, ln_g, ln_b, out);
}

// Round 4
// 119.919 us; speedup vs baseline: 1.0002x; 1.0002x over previous
//
#include <hip/hip_runtime.h>
#include <hip/hip_bf16.h>

#define IH   48
#define IW   48
#define CH   64
#define KS   7
#define LN_EPS 1e-5f
#define QSCALE 0.35355339059327373f
#define L2E    1.4426950408889634f

#define TS   8                   /* output tile side (8x8 = 64 px) */
#define HS   14                  /* halo side: 8 + 2*3 */
#define HP   196                 /* halo pixels 14*14 */
#define KVS  136                 /* kv LDS row stride bf16 (272 B) */
#define AOS  72                  /* q / attn-out LDS row stride bf16 (144 B) */

typedef __bf16 bf16_t;
typedef bf16_t bf16x8 __attribute__((ext_vector_type(8)));
typedef float  f32x4  __attribute__((ext_vector_type(4)));
typedef float  f32x2  __attribute__((ext_vector_type(2)));

__device__ __forceinline__ float bflo(unsigned u) { union { unsigned i; float f; } v; v.i = u << 16; return v.f; }
__device__ __forceinline__ float bfhi(unsigned u) { union { unsigned i; float f; } v; v.i = u & 0xffff0000u; return v.f; }
__device__ __forceinline__ f32x2 unp2(unsigned u) { f32x2 r; r.x = bflo(u); r.y = bfhi(u); return r; }

__device__ __forceinline__ float4 ldf4u(const float* p) {
    float4 r; __builtin_memcpy(&r, p, 16); return r;
}

__device__ __forceinline__ bf16x8 pack_bf16x8(float4 lo, float4 hi) {
    bf16x8 r;
    r[0] = (bf16_t)lo.x; r[1] = (bf16_t)lo.y; r[2] = (bf16_t)lo.z; r[3] = (bf16_t)lo.w;
    r[4] = (bf16_t)hi.x; r[5] = (bf16_t)hi.y; r[6] = (bf16_t)hi.z; r[7] = (bf16_t)hi.w;
    return r;
}

// One block per 8x8 output tile. 512 threads (8 waves), 2 blocks/CU.
// Phase A: QKV projection (MFMA) -> q (LDS) + K/V halo (LDS).
// Phase B: one thread per (pixel, head); 7x7 window FULLY UNROLLED so the
//          compiler can pipeline next-row ds_read/rpb loads under current-row
//          compute with counted waits (r3: non-unrolled loop drained
//          vmcnt(0)+lgkmcnt(0) every row -> all pipes <26% busy).
// Phase C: proj + LN (MFMA), waves 0-3.
__global__ __launch_bounds__(512, 4) void fused_na_kernel(
        const float* __restrict__ x,
        const float* __restrict__ w,      // qkv_w [192][64]
        const float* __restrict__ b,      // qkv_b [192]
        const float* __restrict__ rpb,
        const float* __restrict__ pw,     // proj_w [64][64]
        const float* __restrict__ pb,
        const float* __restrict__ g,
        const float* __restrict__ beta,
        float* __restrict__ out) {
    __shared__ __align__(16) __hip_bfloat16 kv[HP * KVS];    // 53,312 B
    __shared__ __align__(16) __hip_bfloat16 qao[64 * AOS];   //  9,216 B

    const int blk  = blockIdx.x;         // 0..575
    const int n    = blk & 15;           // image
    const int tile = blk >> 4;           // 0..35
    const int i0   = (tile / 6) * TS;
    const int j0   = (tile % 6) * TS;
    int h0 = i0 - 3; h0 = h0 < 0 ? 0 : (h0 > IH - HS ? IH - HS : h0);
    int w0 = j0 - 3; w0 = w0 < 0 ? 0 : (w0 > IW - HS ? IW - HS : w0);
    const int tid = threadIdx.x;
    const size_t img = (size_t)n * (IH * IW);

    // ---------------- phase A: QKV -> LDS --------------------------------
    {
        const int wv = tid >> 6;         // 0..7
        const int l  = tid & 63;
        const int m  = l & 15;
        const int kg = l >> 4;

        // ---- Q: interior 64 px, waves 0-3 (one 16-px m-tile each) ----
        if (wv < 4) {
            const int ch_base = m * 4;
            const float4 bias4 = *(const float4*)(b + ch_base);
            bf16x8 wb0[4], wb1[4];
            #pragma unroll
            for (int t = 0; t < 4; ++t) {
                const float* wr_ = w + (size_t)(ch_base + t) * CH + kg * 8;
                wb0[t] = pack_bf16x8(*(const float4*)(wr_),      *(const float4*)(wr_ + 4));
                wb1[t] = pack_bf16x8(*(const float4*)(wr_ + 32), *(const float4*)(wr_ + 36));
            }
            const int px = wv * 16 + m;
            const int hr = i0 + (px >> 3);
            const int wc = j0 + (px & 7);
            const float* xr = x + (img + hr * IW + wc) * CH + kg * 8;
            const bf16x8 a0 = pack_bf16x8(*(const float4*)(xr),      *(const float4*)(xr + 4));
            const bf16x8 a1 = pack_bf16x8(*(const float4*)(xr + 32), *(const float4*)(xr + 36));
            float val[4][4];
            #pragma unroll
            for (int t = 0; t < 4; ++t) {
                f32x4 acc = {0.f, 0.f, 0.f, 0.f};
                acc = __builtin_amdgcn_mfma_f32_16x16x32_bf16(a0, wb0[t], acc, 0, 0, 0);
                acc = __builtin_amdgcn_mfma_f32_16x16x32_bf16(a1, wb1[t], acc, 0, 0, 0);
                const float bias = (t == 0) ? bias4.x : (t == 1) ? bias4.y : (t == 2) ? bias4.z : bias4.w;
                #pragma unroll
                for (int rr = 0; rr < 4; ++rr) val[t][rr] = (acc[rr] + bias) * (QSCALE * L2E);
            }
            #pragma unroll
            for (int rr = 0; rr < 4; ++rr) {
                const int pix = wv * 16 + kg * 4 + rr;
                union { ushort4 u; __hip_bfloat16 hh[4]; } pk;
                #pragma unroll
                for (int t = 0; t < 4; ++t) pk.hh[t] = __float2bfloat16(val[t][rr]);
                *reinterpret_cast<ushort4*>(qao + pix * AOS + ch_base) = pk.u;
            }
        }

        // ---- K,V: 196 halo px. grp fixed per wave-half; 13 m-tiles / 4 ----
        {
            const int grp = 1 + (wv >> 2);               // waves 0-3: K, 4-7: V
            const int ch_base = grp * 64 + m * 4;
            const float4 bias4 = *(const float4*)(b + ch_base);
            bf16x8 wb0[4], wb1[4];
            #pragma unroll
            for (int t = 0; t < 4; ++t) {
                const float* wr_ = w + (size_t)(ch_base + t) * CH + kg * 8;
                wb0[t] = pack_bf16x8(*(const float4*)(wr_),      *(const float4*)(wr_ + 4));
                wb1[t] = pack_bf16x8(*(const float4*)(wr_ + 32), *(const float4*)(wr_ + 36));
            }
            for (int mt = wv & 3; mt < 13; mt += 4) {
                int hp = mt * 16 + m; if (hp > HP - 1) hp = HP - 1;   // clamped A-row feeds only skipped D-rows
                const int hr = h0 + hp / HS;
                const int wc = w0 + hp % HS;
                const float* xr = x + (img + hr * IW + wc) * CH + kg * 8;
                const bf16x8 a0 = pack_bf16x8(*(const float4*)(xr),      *(const float4*)(xr + 4));
                const bf16x8 a1 = pack_bf16x8(*(const float4*)(xr + 32), *(const float4*)(xr + 36));
                float val[4][4];
                #pragma unroll
                for (int t = 0; t < 4; ++t) {
                    f32x4 acc = {0.f, 0.f, 0.f, 0.f};
                    acc = __builtin_amdgcn_mfma_f32_16x16x32_bf16(a0, wb0[t], acc, 0, 0, 0);
                    acc = __builtin_amdgcn_mfma_f32_16x16x32_bf16(a1, wb1[t], acc, 0, 0, 0);
                    const float bias = (t == 0) ? bias4.x : (t == 1) ? bias4.y : (t == 2) ? bias4.z : bias4.w;
                    #pragma unroll
                    for (int rr = 0; rr < 4; ++rr) val[t][rr] = acc[rr] + bias;
                }
                #pragma unroll
                for (int rr = 0; rr < 4; ++rr) {
                    const int pix = mt * 16 + kg * 4 + rr;
                    if (pix < HP) {
                        union { ushort4 u; __hip_bfloat16 hh[4]; } pk;
                        #pragma unroll
                        for (int t = 0; t < 4; ++t) pk.hh[t] = __float2bfloat16(val[t][rr]);
                        *reinterpret_cast<ushort4*>(kv + pix * KVS + (grp - 1) * 64 + m * 4) = pk.u;
                    }
                }
            }
        }
    }
    __syncthreads();

    // ---------------- phase B: per-(pixel,head) attention, K/V in LDS ----
    {
        const int h  = tid & 7;
        const int px = tid >> 3;             // 0..63
        const int i  = i0 + (px >> 3);
        const int j  = j0 + (px & 7);

        f32x2 q0[4];
        {
            const uint4 u = *reinterpret_cast<const uint4*>(qao + px * AOS + h * 8);
            q0[0] = unp2(u.x); q0[1] = unp2(u.y); q0[2] = unp2(u.z); q0[3] = unp2(u.w);
        }
        __syncthreads();                     // qao region reused for attn-out

        int si = i - 3;  si = si < 0 ? 0 : (si > IH - KS ? IH - KS : si);
        int sj = j - 3;  sj = sj < 0 ? 0 : (sj > IW - KS ? IW - KS : sj);
        const float* rpc = rpb + h * (2*KS-1) * (2*KS-1)
                               + (si - i + (KS-1)) * (2*KS-1) + (sj - j + (KS-1));
        const __hip_bfloat16* kbase = kv + ((si - h0) * HS + (sj - w0)) * KVS + h * 8;

        float lr = 0.f;
        f32x2 a[4];
        #pragma unroll
        for (int d = 0; d < 4; ++d) a[d] = (f32x2){0.f, 0.f};

        #pragma unroll                       // << the change: flatten all 7 rows
        for (int p = 0; p < KS; ++p) {
            const __hip_bfloat16* row = kbase + p * (HS * KVS);
            uint4 kb[KS], vb[KS];
            #pragma unroll
            for (int qq = 0; qq < KS; ++qq) {
                kb[qq] = *reinterpret_cast<const uint4*>(row + qq * KVS);
                vb[qq] = *reinterpret_cast<const uint4*>(row + qq * KVS + 64);
            }
            const float* rr = rpc + p * (2*KS-1);
            const float4 ba = ldf4u(rr);
            const float4 bb = ldf4u(rr + 3);

            float s[KS];
            #pragma unroll
            for (int qq = 0; qq < KS; ++qq) {
                const f32x2 k0 = unp2(kb[qq].x), k1 = unp2(kb[qq].y);
                const f32x2 k2 = unp2(kb[qq].z), k3 = unp2(kb[qq].w);
                f32x2 t = q0[0]*k0 + q0[1]*k1 + q0[2]*k2 + q0[3]*k3;
                s[qq] = t.x + t.y;
            }
            float e[KS];
            e[0] = __builtin_amdgcn_exp2f(fmaf(ba.x, L2E, s[0]));
            e[1] = __builtin_amdgcn_exp2f(fmaf(ba.y, L2E, s[1]));
            e[2] = __builtin_amdgcn_exp2f(fmaf(ba.z, L2E, s[2]));
            e[3] = __builtin_amdgcn_exp2f(fmaf(ba.w, L2E, s[3]));
            e[4] = __builtin_amdgcn_exp2f(fmaf(bb.y, L2E, s[4]));
            e[5] = __builtin_amdgcn_exp2f(fmaf(bb.z, L2E, s[5]));
            e[6] = __builtin_amdgcn_exp2f(fmaf(bb.w, L2E, s[6]));

            #pragma unroll
            for (int qq = 0; qq < KS; ++qq) {
                const f32x2 v0 = unp2(vb[qq].x), v1 = unp2(vb[qq].y);
                const f32x2 v2 = unp2(vb[qq].z), v3 = unp2(vb[qq].w);
                lr += e[qq];
                a[0] += e[qq] * v0; a[1] += e[qq] * v1;
                a[2] += e[qq] * v2; a[3] += e[qq] * v3;
            }
        }
        const float inv = 1.f / lr;
        union { uint4 u; __hip_bfloat16 hh[8]; } pk;
        #pragma unroll
        for (int d = 0; d < 4; ++d) {
            pk.hh[2*d]   = __float2bfloat16(a[d].x * inv);
            pk.hh[2*d+1] = __float2bfloat16(a[d].y * inv);
        }
        *reinterpret_cast<uint4*>(qao + px * AOS + h * 8) = pk.u;
    }
    __syncthreads();

    // ---------------- phase C: proj + LN (waves 0-3, 4 m-tiles) ----------
    if ((tid >> 6) < 4) {
        const int wv = tid >> 6;             // 0..3
        const int l  = tid & 63;
        const int m  = l & 15;
        const int kg = l >> 4;

        const __hip_bfloat16* ar = qao + (wv * 16 + m) * AOS + kg * 8;
        const bf16x8 a0 = *reinterpret_cast<const bf16x8*>(ar);
        const bf16x8 a1 = *reinterpret_cast<const bf16x8*>(ar + 32);

        const int ch_base = m * 4;
        const float4 bias4 = *(const float4*)(pb + ch_base);

        float val[4][4];                                   // [t][r], ch = m*4+t
        #pragma unroll
        for (int t = 0; t < 4; ++t) {
            const float* wr_ = pw + (size_t)(ch_base + t) * CH + kg * 8;  // permuted B row
            const bf16x8 b0 = pack_bf16x8(*(const float4*)(wr_),      *(const float4*)(wr_ + 4));
            const bf16x8 b1 = pack_bf16x8(*(const float4*)(wr_ + 32), *(const float4*)(wr_ + 36));
            f32x4 acc = {0.f, 0.f, 0.f, 0.f};
            acc = __builtin_amdgcn_mfma_f32_16x16x32_bf16(a0, b0, acc, 0, 0, 0);
            acc = __builtin_amdgcn_mfma_f32_16x16x32_bf16(a1, b1, acc, 0, 0, 0);
            const float bias = (t == 0) ? bias4.x : (t == 1) ? bias4.y : (t == 2) ? bias4.z : bias4.w;
            #pragma unroll
            for (int r = 0; r < 4; ++r) val[t][r] = acc[r] + bias;
        }

        float sm[4];
        #pragma unroll
        for (int r = 0; r < 4; ++r) sm[r] = val[0][r] + val[1][r] + val[2][r] + val[3][r];
        #pragma unroll
        for (int mask = 1; mask <= 8; mask <<= 1) {
            #pragma unroll
            for (int r = 0; r < 4; ++r) sm[r] += __shfl_xor(sm[r], mask, 64);
        }
        float mu[4];
        #pragma unroll
        for (int r = 0; r < 4; ++r) mu[r] = sm[r] * (1.f / 64.f);

        float qs[4];
        #pragma unroll
        for (int r = 0; r < 4; ++r) {
            float aa = val[0][r] - mu[r], bq = val[1][r] - mu[r];
            float c  = val[2][r] - mu[r], d  = val[3][r] - mu[r];
            qs[r] = aa * aa + bq * bq + c * c + d * d;
        }
        #pragma unroll
        for (int mask = 1; mask <= 8; mask <<= 1) {
            #pragma unroll
            for (int r = 0; r < 4; ++r) qs[r] += __shfl_xor(qs[r], mask, 64);
        }
        float rs[4];
        #pragma unroll
        for (int r = 0; r < 4; ++r) rs[r] = rsqrtf(qs[r] * (1.f / 64.f) + LN_EPS);

        const float4 g4  = *(const float4*)(g + ch_base);
        const float4 be4 = *(const float4*)(beta + ch_base);
        #pragma unroll
        for (int r = 0; r < 4; ++r) {
            const int pl = wv * 16 + kg * 4 + r;          // local pixel 0..63
            const int gi = i0 + (pl >> 3), gj = j0 + (pl & 7);
            float4 o;
            o.x = (val[0][r] - mu[r]) * rs[r] * g4.x + be4.x;
            o.y = (val[1][r] - mu[r]) * rs[r] * g4.y + be4.y;
            o.z = (val[2][r] - mu[r]) * rs[r] * g4.z + be4.z;
            o.w = (val[3][r] - mu[r]) * rs[r] * g4.w + be4.w;
            *reinterpret_cast<float4*>(out + (img + gi * IW + gj) * CH + ch_base) = o;
        }
    }
}

extern "C" void kernel_launch(void* const* d_in, const int* in_sizes, int n_in,
                              void* d_out, int out_size, void* d_ws, size_t ws_size,
                              hipStream_t stream) {
    const float* x      = (const float*)d_in[0];
    const float* qkv_w  = (const float*)d_in[1];
    const float* qkv_b  = (const float*)d_in[2];
    const float* proj_w = (const float*)d_in[3];
    const float* proj_b = (const float*)d_in[4];
    const float* rpb    = (const float*)d_in[5];
    const float* ln_g   = (const float*)d_in[6];
    const float* ln_b   = (const float*)d_in[7];
    float* out = (float*)d_out;

    fused_na_kernel<<<576, 512, 0, stream>>>(x, qkv_w, qkv_b, rpb,
                                             proj_w, proj_b, ln_g, ln_b, out);
}

// Round 5
// 115.582 us; speedup vs baseline: 1.0377x; 1.0375x over previous
//
#include <hip/hip_runtime.h>
#include <hip/hip_bf16.h>

#define IH   48
#define IW   48
#define CH   64
#define KS   7
#define LN_EPS 1e-5f
#define QSCALE 0.35355339059327373f
#define L2E    1.4426950408889634f

#define TSH  6                   /* tile rows */
#define TSW  12                  /* tile cols */
#define TPX  72                  /* tile pixels = TSH*TSW */
#define HSH  12                  /* halo rows = TSH+6 */
#define HSW  18                  /* halo cols = TSW+6 */
#define HP   216                 /* halo pixels */
#define KVS  136                 /* kv LDS row stride bf16 (272 B, 16B-mult) */
#define AOS  72                  /* q / attn-out LDS row stride bf16 (144 B) */
#define RPBN 1352                /* rpb floats: 8*13*13 */

typedef __bf16 bf16_t;
typedef bf16_t bf16x8 __attribute__((ext_vector_type(8)));
typedef float  f32x4  __attribute__((ext_vector_type(4)));
typedef float  f32x2  __attribute__((ext_vector_type(2)));

__device__ __forceinline__ float bflo(unsigned u) { union { unsigned i; float f; } v; v.i = u << 16; return v.f; }
__device__ __forceinline__ float bfhi(unsigned u) { union { unsigned i; float f; } v; v.i = u & 0xffff0000u; return v.f; }
__device__ __forceinline__ f32x2 unp2(unsigned u) { f32x2 r; r.x = bflo(u); r.y = bfhi(u); return r; }

__device__ __forceinline__ bf16x8 pack_bf16x8(float4 lo, float4 hi) {
    bf16x8 r;
    r[0] = (bf16_t)lo.x; r[1] = (bf16_t)lo.y; r[2] = (bf16_t)lo.z; r[3] = (bf16_t)lo.w;
    r[4] = (bf16_t)hi.x; r[5] = (bf16_t)hi.y; r[6] = (bf16_t)hi.z; r[7] = (bf16_t)hi.w;
    return r;
}

// Grid restructure (r5): 512 blocks = 16 img x 32 tiles (6x12) = EXACTLY
// 2 blocks/CU, all resident from t=0 -> no straggler round (r1-r4: 576
// blocks on 512 slots left 192 CUs idle for ~half the kernel; avg occupancy
// 26% of the 50% launched). 576 thr = 9 waves -> 18 waves/CU.
// rpb is staged to LDS once per block: phase B's inner loop becomes pure
// LDS+VALU (was: 7 per-row scattered global loads, ~200cy VMEM wait each on
// the rolled loop's critical path).
// NOTE: VGPR must stay <=64 for 5-wave SIMDs (occupancy halves at 64).
__global__ __launch_bounds__(576, 5) void fused_na_kernel(
        const float* __restrict__ x,
        const float* __restrict__ w,      // qkv_w [192][64]
        const float* __restrict__ b,      // qkv_b [192]
        const float* __restrict__ rpb,
        const float* __restrict__ pw,     // proj_w [64][64]
        const float* __restrict__ pb,
        const float* __restrict__ g,
        const float* __restrict__ beta,
        float* __restrict__ out) {
    __shared__ __align__(16) __hip_bfloat16 kv[HP * KVS];    // 58,752 B
    __shared__ __align__(16) __hip_bfloat16 qao[TPX * AOS];  // 10,368 B
    __shared__ __align__(16) float rpbl[RPBN];               //  5,408 B

    const int blk  = blockIdx.x;         // 0..511
    const int n    = blk & 15;           // image
    const int tile = blk >> 4;           // 0..31
    const int i0   = (tile >> 2) * TSH;  // 8 row-tiles
    const int j0   = (tile & 3) * TSW;   // 4 col-tiles
    int h0 = i0 - 3; h0 = h0 < 0 ? 0 : (h0 > IH - HSH ? IH - HSH : h0);
    int w0 = j0 - 3; w0 = w0 < 0 ? 0 : (w0 > IW - HSW ? IW - HSW : w0);
    const int tid = threadIdx.x;
    const size_t img = (size_t)n * (IH * IW);

    // ---- rpb -> LDS (coalesced, ~3 dwords/thread) ----
    for (int idx = tid; idx < RPBN; idx += 576) rpbl[idx] = rpb[idx];

    // ---------------- phase A: QKV -> LDS --------------------------------
    {
        const int wv = tid >> 6;         // 0..8
        const int l  = tid & 63;
        const int m  = l & 15;
        const int kg = l >> 4;

        if (wv == 8) {
            // ---- Q: 72 interior px = 5 m-tiles (last half-masked) ----
            const int ch_base = m * 4;
            const float4 bias4 = *(const float4*)(b + ch_base);
            bf16x8 wb0[4], wb1[4];
            #pragma unroll
            for (int t = 0; t < 4; ++t) {
                const float* wr_ = w + (size_t)(ch_base + t) * CH + kg * 8;
                wb0[t] = pack_bf16x8(*(const float4*)(wr_),      *(const float4*)(wr_ + 4));
                wb1[t] = pack_bf16x8(*(const float4*)(wr_ + 32), *(const float4*)(wr_ + 36));
            }
            for (int mt = 0; mt < 5; ++mt) {
                int px = mt * 16 + m; if (px > TPX - 1) px = TPX - 1;  // clamped A-rows feed only masked D-rows
                const int hr = i0 + px / TSW;
                const int wc = j0 + px % TSW;
                const float* xr = x + (img + hr * IW + wc) * CH + kg * 8;
                const bf16x8 a0 = pack_bf16x8(*(const float4*)(xr),      *(const float4*)(xr + 4));
                const bf16x8 a1 = pack_bf16x8(*(const float4*)(xr + 32), *(const float4*)(xr + 36));
                float val[4][4];
                #pragma unroll
                for (int t = 0; t < 4; ++t) {
                    f32x4 acc = {0.f, 0.f, 0.f, 0.f};
                    acc = __builtin_amdgcn_mfma_f32_16x16x32_bf16(a0, wb0[t], acc, 0, 0, 0);
                    acc = __builtin_amdgcn_mfma_f32_16x16x32_bf16(a1, wb1[t], acc, 0, 0, 0);
                    const float bias = (t == 0) ? bias4.x : (t == 1) ? bias4.y : (t == 2) ? bias4.z : bias4.w;
                    #pragma unroll
                    for (int rr = 0; rr < 4; ++rr) val[t][rr] = (acc[rr] + bias) * (QSCALE * L2E);
                }
                #pragma unroll
                for (int rr = 0; rr < 4; ++rr) {
                    const int pix = mt * 16 + kg * 4 + rr;
                    if (pix < TPX) {
                        union { ushort4 u; __hip_bfloat16 hh[4]; } pk;
                        #pragma unroll
                        for (int t = 0; t < 4; ++t) pk.hh[t] = __float2bfloat16(val[t][rr]);
                        *reinterpret_cast<ushort4*>(qao + pix * AOS + ch_base) = pk.u;
                    }
                }
            }
        } else {
            // ---- K,V: 216 halo px = 14 m-tiles (last half-masked) x 2 grps
            const int grp = 1 + (wv >> 2);               // waves 0-3: K, 4-7: V
            const int wg  = wv & 3;
            const int ch_base = grp * 64 + m * 4;
            const float4 bias4 = *(const float4*)(b + ch_base);
            bf16x8 wb0[4], wb1[4];
            #pragma unroll
            for (int t = 0; t < 4; ++t) {
                const float* wr_ = w + (size_t)(ch_base + t) * CH + kg * 8;
                wb0[t] = pack_bf16x8(*(const float4*)(wr_),      *(const float4*)(wr_ + 4));
                wb1[t] = pack_bf16x8(*(const float4*)(wr_ + 32), *(const float4*)(wr_ + 36));
            }
            for (int mt = wg; mt < 14; mt += 4) {
                int hp = mt * 16 + m; if (hp > HP - 1) hp = HP - 1;   // clamped A-rows feed only masked D-rows
                const int hr = h0 + hp / HSW;
                const int wc = w0 + hp % HSW;
                const float* xr = x + (img + hr * IW + wc) * CH + kg * 8;
                const bf16x8 a0 = pack_bf16x8(*(const float4*)(xr),      *(const float4*)(xr + 4));
                const bf16x8 a1 = pack_bf16x8(*(const float4*)(xr + 32), *(const float4*)(xr + 36));
                float val[4][4];
                #pragma unroll
                for (int t = 0; t < 4; ++t) {
                    f32x4 acc = {0.f, 0.f, 0.f, 0.f};
                    acc = __builtin_amdgcn_mfma_f32_16x16x32_bf16(a0, wb0[t], acc, 0, 0, 0);
                    acc = __builtin_amdgcn_mfma_f32_16x16x32_bf16(a1, wb1[t], acc, 0, 0, 0);
                    const float bias = (t == 0) ? bias4.x : (t == 1) ? bias4.y : (t == 2) ? bias4.z : bias4.w;
                    #pragma unroll
                    for (int rr = 0; rr < 4; ++rr) val[t][rr] = acc[rr] + bias;
                }
                #pragma unroll
                for (int rr = 0; rr < 4; ++rr) {
                    const int pix = mt * 16 + kg * 4 + rr;
                    if (pix < HP) {
                        union { ushort4 u; __hip_bfloat16 hh[4]; } pk;
                        #pragma unroll
                        for (int t = 0; t < 4; ++t) pk.hh[t] = __float2bfloat16(val[t][rr]);
                        *reinterpret_cast<ushort4*>(kv + pix * KVS + (grp - 1) * 64 + m * 4) = pk.u;
                    }
                }
            }
        }
    }
    __syncthreads();

    // ---------------- phase B: per-(pixel,head) attention, all from LDS --
    {
        const int h  = tid & 7;
        const int px = tid >> 3;             // 0..71
        const int i  = i0 + px / TSW;
        const int j  = j0 + px % TSW;

        f32x2 q0[4];
        {
            const uint4 u = *reinterpret_cast<const uint4*>(qao + px * AOS + h * 8);
            q0[0] = unp2(u.x); q0[1] = unp2(u.y); q0[2] = unp2(u.z); q0[3] = unp2(u.w);
        }
        __syncthreads();                     // qao region reused for attn-out

        int si = i - 3;  si = si < 0 ? 0 : (si > IH - KS ? IH - KS : si);
        int sj = j - 3;  sj = sj < 0 ? 0 : (sj > IW - KS ? IW - KS : sj);
        const float* rpc = rpbl + h * (2*KS-1) * (2*KS-1)
                                + (si - i + (KS-1)) * (2*KS-1) + (sj - j + (KS-1));
        const __hip_bfloat16* kbase = kv + ((si - h0) * HSW + (sj - w0)) * KVS + h * 8;

        float lr = 0.f;
        f32x2 a[4];
        #pragma unroll
        for (int d = 0; d < 4; ++d) a[d] = (f32x2){0.f, 0.f};

        for (int p = 0; p < KS; ++p) {       // uniform 7 rows, no divergence
            const __hip_bfloat16* row = kbase + p * (HSW * KVS);
            uint4 kb[KS], vb[KS];
            #pragma unroll
            for (int qq = 0; qq < KS; ++qq) {
                kb[qq] = *reinterpret_cast<const uint4*>(row + qq * KVS);
                vb[qq] = *reinterpret_cast<const uint4*>(row + qq * KVS + 64);
            }
            float bl[KS];
            #pragma unroll
            for (int qq = 0; qq < KS; ++qq) bl[qq] = rpc[p * (2*KS-1) + qq];

            float s[KS];
            #pragma unroll
            for (int qq = 0; qq < KS; ++qq) {
                const f32x2 k0 = unp2(kb[qq].x), k1 = unp2(kb[qq].y);
                const f32x2 k2 = unp2(kb[qq].z), k3 = unp2(kb[qq].w);
                f32x2 t = q0[0]*k0 + q0[1]*k1 + q0[2]*k2 + q0[3]*k3;
                s[qq] = t.x + t.y;
            }
            float e[KS];
            #pragma unroll
            for (int qq = 0; qq < KS; ++qq)
                e[qq] = __builtin_amdgcn_exp2f(fmaf(bl[qq], L2E, s[qq]));

            #pragma unroll
            for (int qq = 0; qq < KS; ++qq) {
                const f32x2 v0 = unp2(vb[qq].x), v1 = unp2(vb[qq].y);
                const f32x2 v2 = unp2(vb[qq].z), v3 = unp2(vb[qq].w);
                lr += e[qq];
                a[0] += e[qq] * v0; a[1] += e[qq] * v1;
                a[2] += e[qq] * v2; a[3] += e[qq] * v3;
            }
        }
        const float inv = 1.f / lr;
        union { uint4 u; __hip_bfloat16 hh[8]; } pk;
        #pragma unroll
        for (int d = 0; d < 4; ++d) {
            pk.hh[2*d]   = __float2bfloat16(a[d].x * inv);
            pk.hh[2*d+1] = __float2bfloat16(a[d].y * inv);
        }
        *reinterpret_cast<uint4*>(qao + px * AOS + h * 8) = pk.u;
    }
    __syncthreads();

    // ---------------- phase C: proj + LN (waves 0-4, last half-masked) ---
    if ((tid >> 6) < 5) {
        const int wv = tid >> 6;             // 0..4
        const int l  = tid & 63;
        const int m  = l & 15;
        const int kg = l >> 4;

        int ap = wv * 16 + m; if (ap > TPX - 1) ap = TPX - 1;  // clamped A-rows feed only masked D-rows
        const __hip_bfloat16* ar = qao + ap * AOS + kg * 8;
        const bf16x8 a0 = *reinterpret_cast<const bf16x8*>(ar);
        const bf16x8 a1 = *reinterpret_cast<const bf16x8*>(ar + 32);

        const int ch_base = m * 4;
        const float4 bias4 = *(const float4*)(pb + ch_base);

        float val[4][4];                                   // [t][r], ch = m*4+t
        #pragma unroll
        for (int t = 0; t < 4; ++t) {
            const float* wr_ = pw + (size_t)(ch_base + t) * CH + kg * 8;  // permuted B row
            const bf16x8 b0 = pack_bf16x8(*(const float4*)(wr_),      *(const float4*)(wr_ + 4));
            const bf16x8 b1 = pack_bf16x8(*(const float4*)(wr_ + 32), *(const float4*)(wr_ + 36));
            f32x4 acc = {0.f, 0.f, 0.f, 0.f};
            acc = __builtin_amdgcn_mfma_f32_16x16x32_bf16(a0, b0, acc, 0, 0, 0);
            acc = __builtin_amdgcn_mfma_f32_16x16x32_bf16(a1, b1, acc, 0, 0, 0);
            const float bias = (t == 0) ? bias4.x : (t == 1) ? bias4.y : (t == 2) ? bias4.z : bias4.w;
            #pragma unroll
            for (int r = 0; r < 4; ++r) val[t][r] = acc[r] + bias;
        }

        float sm[4];
        #pragma unroll
        for (int r = 0; r < 4; ++r) sm[r] = val[0][r] + val[1][r] + val[2][r] + val[3][r];
        #pragma unroll
        for (int mask = 1; mask <= 8; mask <<= 1) {
            #pragma unroll
            for (int r = 0; r < 4; ++r) sm[r] += __shfl_xor(sm[r], mask, 64);
        }
        float mu[4];
        #pragma unroll
        for (int r = 0; r < 4; ++r) mu[r] = sm[r] * (1.f / 64.f);

        float qs[4];
        #pragma unroll
        for (int r = 0; r < 4; ++r) {
            float aa = val[0][r] - mu[r], bq = val[1][r] - mu[r];
            float c  = val[2][r] - mu[r], d  = val[3][r] - mu[r];
            qs[r] = aa * aa + bq * bq + c * c + d * d;
        }
        #pragma unroll
        for (int mask = 1; mask <= 8; mask <<= 1) {
            #pragma unroll
            for (int r = 0; r < 4; ++r) qs[r] += __shfl_xor(qs[r], mask, 64);
        }
        float rs[4];
        #pragma unroll
        for (int r = 0; r < 4; ++r) rs[r] = rsqrtf(qs[r] * (1.f / 64.f) + LN_EPS);

        const float4 g4  = *(const float4*)(g + ch_base);
        const float4 be4 = *(const float4*)(beta + ch_base);
        #pragma unroll
        for (int r = 0; r < 4; ++r) {
            const int pl = wv * 16 + kg * 4 + r;          // local pixel
            if (pl < TPX) {
                const int gi = i0 + pl / TSW, gj = j0 + pl % TSW;
                float4 o;
                o.x = (val[0][r] - mu[r]) * rs[r] * g4.x + be4.x;
                o.y = (val[1][r] - mu[r]) * rs[r] * g4.y + be4.y;
                o.z = (val[2][r] - mu[r]) * rs[r] * g4.z + be4.z;
                o.w = (val[3][r] - mu[r]) * rs[r] * g4.w + be4.w;
                *reinterpret_cast<float4*>(out + (img + gi * IW + gj) * CH + ch_base) = o;
            }
        }
    }
}

extern "C" void kernel_launch(void* const* d_in, const int* in_sizes, int n_in,
                              void* d_out, int out_size, void* d_ws, size_t ws_size,
                              hipStream_t stream) {
    const float* x      = (const float*)d_in[0];
    const float* qkv_w  = (const float*)d_in[1];
    const float* qkv_b  = (const float*)d_in[2];
    const float* proj_w = (const float*)d_in[3];
    const float* proj_b = (const float*)d_in[4];
    const float* rpb    = (const float*)d_in[5];
    const float* ln_g   = (const float*)d_in[6];
    const float* ln_b   = (const float*)d_in[7];
    float* out = (float*)d_out;

    fused_na_kernel<<<512, 576, 0, stream>>>(x, qkv_w, qkv_b, rpb,
                                             proj_w, proj_b, ln_g, ln_b, out);
}

// Round 6
// 114.254 us; speedup vs baseline: 1.0498x; 1.0116x over previous
//
#include <hip/hip_runtime.h>
#include <hip/hip_bf16.h>

#define IH   48
#define IW   48
#define CH   64
#define KS   7
#define LN_EPS 1e-5f
#define QSCALE 0.35355339059327373f
#define L2E    1.4426950408889634f

#define TSH  6                   /* tile rows */
#define TSW  12                  /* tile cols */
#define TPX  72                  /* tile pixels = TSH*TSW */
#define HSH  12                  /* halo rows = TSH+6 */
#define HSW  18                  /* halo cols = TSW+6 */
#define HP   216                 /* halo pixels */
#define KVS  136                 /* kv LDS row stride bf16 (272 B, 16B-mult) */
#define AOS  72                  /* q / attn-out LDS row stride bf16 (144 B) */
#define RPBN 1352                /* rpb floats: 8*13*13 */

typedef __bf16 bf16_t;
typedef bf16_t bf16x8 __attribute__((ext_vector_type(8)));
typedef float  f32x4  __attribute__((ext_vector_type(4)));
typedef float  f32x2  __attribute__((ext_vector_type(2)));

__device__ __forceinline__ float bflo(unsigned u) { union { unsigned i; float f; } v; v.i = u << 16; return v.f; }
__device__ __forceinline__ float bfhi(unsigned u) { union { unsigned i; float f; } v; v.i = u & 0xffff0000u; return v.f; }
__device__ __forceinline__ f32x2 unp2(unsigned u) { f32x2 r; r.x = bflo(u); r.y = bfhi(u); return r; }

__device__ __forceinline__ bf16x8 pack_bf16x8(float4 lo, float4 hi) {
    bf16x8 r;
    r[0] = (bf16_t)lo.x; r[1] = (bf16_t)lo.y; r[2] = (bf16_t)lo.z; r[3] = (bf16_t)lo.w;
    r[4] = (bf16_t)hi.x; r[5] = (bf16_t)hi.y; r[6] = (bf16_t)hi.z; r[7] = (bf16_t)hi.w;
    return r;
}

// r6: phase B row body groups ALL 14 ds_read_b128 + 7 rpb reads, then a
// sched_barrier(0), then the compute. r5's VGPR=48 proves the compiler chose
// a register-minimal schedule (kb[7]+vb[7]=56 VGPR can't fit in 48): it was
// splitting each row into 3-4 serialized ~120cy LDS-latency rounds -> per-wave
// VALU duty ~6% (measured VALUBusy 27% / 4.5 waves/SIMD). The barrier forces
// one latency exposure per row. Confirming signal: VGPR ~48 -> ~95.
__global__ __launch_bounds__(576, 5) void fused_na_kernel(
        const float* __restrict__ x,
        const float* __restrict__ w,      // qkv_w [192][64]
        const float* __restrict__ b,      // qkv_b [192]
        const float* __restrict__ rpb,
        const float* __restrict__ pw,     // proj_w [64][64]
        const float* __restrict__ pb,
        const float* __restrict__ g,
        const float* __restrict__ beta,
        float* __restrict__ out) {
    __shared__ __align__(16) __hip_bfloat16 kv[HP * KVS];    // 58,752 B
    __shared__ __align__(16) __hip_bfloat16 qao[TPX * AOS];  // 10,368 B
    __shared__ __align__(16) float rpbl[RPBN];               //  5,408 B

    const int blk  = blockIdx.x;         // 0..511
    const int n    = blk & 15;           // image
    const int tile = blk >> 4;           // 0..31
    const int i0   = (tile >> 2) * TSH;  // 8 row-tiles
    const int j0   = (tile & 3) * TSW;   // 4 col-tiles
    int h0 = i0 - 3; h0 = h0 < 0 ? 0 : (h0 > IH - HSH ? IH - HSH : h0);
    int w0 = j0 - 3; w0 = w0 < 0 ? 0 : (w0 > IW - HSW ? IW - HSW : w0);
    const int tid = threadIdx.x;
    const size_t img = (size_t)n * (IH * IW);

    // ---- rpb -> LDS (coalesced, ~3 dwords/thread) ----
    for (int idx = tid; idx < RPBN; idx += 576) rpbl[idx] = rpb[idx];

    // ---------------- phase A: QKV -> LDS --------------------------------
    {
        const int wv = tid >> 6;         // 0..8
        const int l  = tid & 63;
        const int m  = l & 15;
        const int kg = l >> 4;

        if (wv == 8) {
            // ---- Q: 72 interior px = 5 m-tiles (last half-masked) ----
            const int ch_base = m * 4;
            const float4 bias4 = *(const float4*)(b + ch_base);
            bf16x8 wb0[4], wb1[4];
            #pragma unroll
            for (int t = 0; t < 4; ++t) {
                const float* wr_ = w + (size_t)(ch_base + t) * CH + kg * 8;
                wb0[t] = pack_bf16x8(*(const float4*)(wr_),      *(const float4*)(wr_ + 4));
                wb1[t] = pack_bf16x8(*(const float4*)(wr_ + 32), *(const float4*)(wr_ + 36));
            }
            for (int mt = 0; mt < 5; ++mt) {
                int px = mt * 16 + m; if (px > TPX - 1) px = TPX - 1;  // clamped A-rows feed only masked D-rows
                const int hr = i0 + px / TSW;
                const int wc = j0 + px % TSW;
                const float* xr = x + (img + hr * IW + wc) * CH + kg * 8;
                const bf16x8 a0 = pack_bf16x8(*(const float4*)(xr),      *(const float4*)(xr + 4));
                const bf16x8 a1 = pack_bf16x8(*(const float4*)(xr + 32), *(const float4*)(xr + 36));
                float val[4][4];
                #pragma unroll
                for (int t = 0; t < 4; ++t) {
                    f32x4 acc = {0.f, 0.f, 0.f, 0.f};
                    acc = __builtin_amdgcn_mfma_f32_16x16x32_bf16(a0, wb0[t], acc, 0, 0, 0);
                    acc = __builtin_amdgcn_mfma_f32_16x16x32_bf16(a1, wb1[t], acc, 0, 0, 0);
                    const float bias = (t == 0) ? bias4.x : (t == 1) ? bias4.y : (t == 2) ? bias4.z : bias4.w;
                    #pragma unroll
                    for (int rr = 0; rr < 4; ++rr) val[t][rr] = (acc[rr] + bias) * (QSCALE * L2E);
                }
                #pragma unroll
                for (int rr = 0; rr < 4; ++rr) {
                    const int pix = mt * 16 + kg * 4 + rr;
                    if (pix < TPX) {
                        union { ushort4 u; __hip_bfloat16 hh[4]; } pk;
                        #pragma unroll
                        for (int t = 0; t < 4; ++t) pk.hh[t] = __float2bfloat16(val[t][rr]);
                        *reinterpret_cast<ushort4*>(qao + pix * AOS + ch_base) = pk.u;
                    }
                }
            }
        } else {
            // ---- K,V: 216 halo px = 14 m-tiles (last half-masked) x 2 grps
            const int grp = 1 + (wv >> 2);               // waves 0-3: K, 4-7: V
            const int wg  = wv & 3;
            const int ch_base = grp * 64 + m * 4;
            const float4 bias4 = *(const float4*)(b + ch_base);
            bf16x8 wb0[4], wb1[4];
            #pragma unroll
            for (int t = 0; t < 4; ++t) {
                const float* wr_ = w + (size_t)(ch_base + t) * CH + kg * 8;
                wb0[t] = pack_bf16x8(*(const float4*)(wr_),      *(const float4*)(wr_ + 4));
                wb1[t] = pack_bf16x8(*(const float4*)(wr_ + 32), *(const float4*)(wr_ + 36));
            }
            for (int mt = wg; mt < 14; mt += 4) {
                int hp = mt * 16 + m; if (hp > HP - 1) hp = HP - 1;   // clamped A-rows feed only masked D-rows
                const int hr = h0 + hp / HSW;
                const int wc = w0 + hp % HSW;
                const float* xr = x + (img + hr * IW + wc) * CH + kg * 8;
                const bf16x8 a0 = pack_bf16x8(*(const float4*)(xr),      *(const float4*)(xr + 4));
                const bf16x8 a1 = pack_bf16x8(*(const float4*)(xr + 32), *(const float4*)(xr + 36));
                float val[4][4];
                #pragma unroll
                for (int t = 0; t < 4; ++t) {
                    f32x4 acc = {0.f, 0.f, 0.f, 0.f};
                    acc = __builtin_amdgcn_mfma_f32_16x16x32_bf16(a0, wb0[t], acc, 0, 0, 0);
                    acc = __builtin_amdgcn_mfma_f32_16x16x32_bf16(a1, wb1[t], acc, 0, 0, 0);
                    const float bias = (t == 0) ? bias4.x : (t == 1) ? bias4.y : (t == 2) ? bias4.z : bias4.w;
                    #pragma unroll
                    for (int rr = 0; rr < 4; ++rr) val[t][rr] = acc[rr] + bias;
                }
                #pragma unroll
                for (int rr = 0; rr < 4; ++rr) {
                    const int pix = mt * 16 + kg * 4 + rr;
                    if (pix < HP) {
                        union { ushort4 u; __hip_bfloat16 hh[4]; } pk;
                        #pragma unroll
                        for (int t = 0; t < 4; ++t) pk.hh[t] = __float2bfloat16(val[t][rr]);
                        *reinterpret_cast<ushort4*>(kv + pix * KVS + (grp - 1) * 64 + m * 4) = pk.u;
                    }
                }
            }
        }
    }
    __syncthreads();

    // ---------------- phase B: per-(pixel,head) attention, all from LDS --
    {
        const int h  = tid & 7;
        const int px = tid >> 3;             // 0..71
        const int i  = i0 + px / TSW;
        const int j  = j0 + px % TSW;

        f32x2 q0[4];
        {
            const uint4 u = *reinterpret_cast<const uint4*>(qao + px * AOS + h * 8);
            q0[0] = unp2(u.x); q0[1] = unp2(u.y); q0[2] = unp2(u.z); q0[3] = unp2(u.w);
        }
        __syncthreads();                     // qao region reused for attn-out

        int si = i - 3;  si = si < 0 ? 0 : (si > IH - KS ? IH - KS : si);
        int sj = j - 3;  sj = sj < 0 ? 0 : (sj > IW - KS ? IW - KS : sj);
        const float* rpc = rpbl + h * (2*KS-1) * (2*KS-1)
                                + (si - i + (KS-1)) * (2*KS-1) + (sj - j + (KS-1));
        const __hip_bfloat16* kbase = kv + ((si - h0) * HSW + (sj - w0)) * KVS + h * 8;

        float lr = 0.f;
        f32x2 a[4];
        #pragma unroll
        for (int d = 0; d < 4; ++d) a[d] = (f32x2){0.f, 0.f};

        for (int p = 0; p < KS; ++p) {       // uniform 7 rows, no divergence
            const __hip_bfloat16* row = kbase + p * (HSW * KVS);
            // ---- issue the FULL row's loads before any consume ----
            uint4 kb[KS], vb[KS];
            float bl[KS];
            #pragma unroll
            for (int qq = 0; qq < KS; ++qq)
                kb[qq] = *reinterpret_cast<const uint4*>(row + qq * KVS);
            #pragma unroll
            for (int qq = 0; qq < KS; ++qq)
                vb[qq] = *reinterpret_cast<const uint4*>(row + qq * KVS + 64);
            #pragma unroll
            for (int qq = 0; qq < KS; ++qq)
                bl[qq] = rpc[p * (2*KS-1) + qq];
            // nothing may cross: forces all 21 loads in flight (56+ VGPR live)
            __builtin_amdgcn_sched_barrier(0);

            float s[KS];
            #pragma unroll
            for (int qq = 0; qq < KS; ++qq) {
                const f32x2 k0 = unp2(kb[qq].x), k1 = unp2(kb[qq].y);
                const f32x2 k2 = unp2(kb[qq].z), k3 = unp2(kb[qq].w);
                f32x2 t = q0[0]*k0 + q0[1]*k1 + q0[2]*k2 + q0[3]*k3;
                s[qq] = t.x + t.y;
            }
            float e[KS];
            #pragma unroll
            for (int qq = 0; qq < KS; ++qq)
                e[qq] = __builtin_amdgcn_exp2f(fmaf(bl[qq], L2E, s[qq]));

            #pragma unroll
            for (int qq = 0; qq < KS; ++qq) {
                const f32x2 v0 = unp2(vb[qq].x), v1 = unp2(vb[qq].y);
                const f32x2 v2 = unp2(vb[qq].z), v3 = unp2(vb[qq].w);
                lr += e[qq];
                a[0] += e[qq] * v0; a[1] += e[qq] * v1;
                a[2] += e[qq] * v2; a[3] += e[qq] * v3;
            }
        }
        const float inv = 1.f / lr;
        union { uint4 u; __hip_bfloat16 hh[8]; } pk;
        #pragma unroll
        for (int d = 0; d < 4; ++d) {
            pk.hh[2*d]   = __float2bfloat16(a[d].x * inv);
            pk.hh[2*d+1] = __float2bfloat16(a[d].y * inv);
        }
        *reinterpret_cast<uint4*>(qao + px * AOS + h * 8) = pk.u;
    }
    __syncthreads();

    // ---------------- phase C: proj + LN (waves 0-4, last half-masked) ---
    if ((tid >> 6) < 5) {
        const int wv = tid >> 6;             // 0..4
        const int l  = tid & 63;
        const int m  = l & 15;
        const int kg = l >> 4;

        int ap = wv * 16 + m; if (ap > TPX - 1) ap = TPX - 1;  // clamped A-rows feed only masked D-rows
        const __hip_bfloat16* ar = qao + ap * AOS + kg * 8;
        const bf16x8 a0 = *reinterpret_cast<const bf16x8*>(ar);
        const bf16x8 a1 = *reinterpret_cast<const bf16x8*>(ar + 32);

        const int ch_base = m * 4;
        const float4 bias4 = *(const float4*)(pb + ch_base);

        float val[4][4];                                   // [t][r], ch = m*4+t
        #pragma unroll
        for (int t = 0; t < 4; ++t) {
            const float* wr_ = pw + (size_t)(ch_base + t) * CH + kg * 8;  // permuted B row
            const bf16x8 b0 = pack_bf16x8(*(const float4*)(wr_),      *(const float4*)(wr_ + 4));
            const bf16x8 b1 = pack_bf16x8(*(const float4*)(wr_ + 32), *(const float4*)(wr_ + 36));
            f32x4 acc = {0.f, 0.f, 0.f, 0.f};
            acc = __builtin_amdgcn_mfma_f32_16x16x32_bf16(a0, b0, acc, 0, 0, 0);
            acc = __builtin_amdgcn_mfma_f32_16x16x32_bf16(a1, b1, acc, 0, 0, 0);
            const float bias = (t == 0) ? bias4.x : (t == 1) ? bias4.y : (t == 2) ? bias4.z : bias4.w;
            #pragma unroll
            for (int r = 0; r < 4; ++r) val[t][r] = acc[r] + bias;
        }

        float sm[4];
        #pragma unroll
        for (int r = 0; r < 4; ++r) sm[r] = val[0][r] + val[1][r] + val[2][r] + val[3][r];
        #pragma unroll
        for (int mask = 1; mask <= 8; mask <<= 1) {
            #pragma unroll
            for (int r = 0; r < 4; ++r) sm[r] += __shfl_xor(sm[r], mask, 64);
        }
        float mu[4];
        #pragma unroll
        for (int r = 0; r < 4; ++r) mu[r] = sm[r] * (1.f / 64.f);

        float qs[4];
        #pragma unroll
        for (int r = 0; r < 4; ++r) {
            float aa = val[0][r] - mu[r], bq = val[1][r] - mu[r];
            float c  = val[2][r] - mu[r], d  = val[3][r] - mu[r];
            qs[r] = aa * aa + bq * bq + c * c + d * d;
        }
        #pragma unroll
        for (int mask = 1; mask <= 8; mask <<= 1) {
            #pragma unroll
            for (int r = 0; r < 4; ++r) qs[r] += __shfl_xor(qs[r], mask, 64);
        }
        float rs[4];
        #pragma unroll
        for (int r = 0; r < 4; ++r) rs[r] = rsqrtf(qs[r] * (1.f / 64.f) + LN_EPS);

        const float4 g4  = *(const float4*)(g + ch_base);
        const float4 be4 = *(const float4*)(beta + ch_base);
        #pragma unroll
        for (int r = 0; r < 4; ++r) {
            const int pl = wv * 16 + kg * 4 + r;          // local pixel
            if (pl < TPX) {
                const int gi = i0 + pl / TSW, gj = j0 + pl % TSW;
                float4 o;
                o.x = (val[0][r] - mu[r]) * rs[r] * g4.x + be4.x;
                o.y = (val[1][r] - mu[r]) * rs[r] * g4.y + be4.y;
                o.z = (val[2][r] - mu[r]) * rs[r] * g4.z + be4.z;
                o.w = (val[3][r] - mu[r]) * rs[r] * g4.w + be4.w;
                *reinterpret_cast<float4*>(out + (img + gi * IW + gj) * CH + ch_base) = o;
            }
        }
    }
}

extern "C" void kernel_launch(void* const* d_in, const int* in_sizes, int n_in,
                              void* d_out, int out_size, void* d_ws, size_t ws_size,
                              hipStream_t stream) {
    const float* x      = (const float*)d_in[0];
    const float* qkv_w  = (const float*)d_in[1];
    const float* qkv_b  = (const float*)d_in[2];
    const float* proj_w = (const float*)d_in[3];
    const float* proj_b = (const float*)d_in[4];
    const float* rpb    = (const float*)d_in[5];
    const float* ln_g   = (const float*)d_in[6];
    const float* ln_b   = (const float*)d_in[7];
    float* out = (float*)d_out;

    fused_na_kernel<<<512, 576, 0, stream>>>(x, qkv_w, qkv_b, rpb,
                                             proj_w, proj_b, ln_g, ln_b, out);
}